// Round 7
// baseline (381.430 us; speedup 1.0000x reference)
//
#include <hip/hip_runtime.h>
#include <hip/hip_bf16.h>

// Problem constants (fixed by setup_inputs)
#define NB 4
#define SEQ 2048
#define HID 768
#define NSPAN 16384            // spans per batch
#define M_TOT (NB * NSPAN)     // 65536 rows
#define K2 1536                // 2*HID
#define NTILE 24               // K2 / 64
#define CMP_CAP 66048          // compacted-table capacity = 258*256
#define NWG 774                // GEMM grid: 258 m-tiles * 3 n-strips

typedef float f32x4 __attribute__((ext_vector_type(4)));
typedef short s16x8 __attribute__((ext_vector_type(8)));
using bf16 = __hip_bfloat16;

// global -> LDS direct (16B per lane). Dest is wave-uniform base (HW adds
// lane*16); global src is per-lane (gather-capable).
__device__ __forceinline__ void gll16(const void* g, void* l) {
    __builtin_amdgcn_global_load_lds(
        (const __attribute__((address_space(1))) unsigned*)g,
        (__attribute__((address_space(3))) unsigned*)l, 16, 0, 0);
}

// ---------------------------------------------------------------------------
__global__ void mask_detect_kernel(const unsigned* __restrict__ masks, int* __restrict__ flag) {
    int t = blockIdx.x * 256 + threadIdx.x;
    if (t < 16384) {
        unsigned v = masks[t];
        if (v > 1u) atomicOr(flag, 1);   // multi-byte pattern => byte-packed bools
    }
}

__device__ __forceinline__ bool mask_at(const int* masks, int u8, int m) {
    return u8 ? (((const unsigned char*)masks)[m] != 0) : (masks[m] != 0);
}

// ---------------------------------------------------------------------------
__global__ void init_compact_kernel(int* __restrict__ cS, int* __restrict__ cE,
                                    int* __restrict__ cO) {
    int i = blockIdx.x * 256 + threadIdx.x;
    if (i < CMP_CAP) { cS[i] = 0; cE[i] = 0; cO[i] = -1; }
}

// ---------------------------------------------------------------------------
__global__ void count_kernel(const int* __restrict__ masks, const int* __restrict__ flag,
                             int* __restrict__ blockCnt) {
    int bid = blockIdx.x, tid = threadIdx.x;
    bool act = mask_at(masks, flag[0], bid * 256 + tid);
    unsigned long long b = __ballot(act);
    __shared__ int wc[4];
    if ((tid & 63) == 0) wc[tid >> 6] = __popcll(b);
    __syncthreads();
    if (tid == 0) blockCnt[bid] = wc[0] + wc[1] + wc[2] + wc[3];
}

__global__ void scan_kernel(const int* __restrict__ blockCnt, int* __restrict__ blockOff,
                            int* __restrict__ cnt) {
    __shared__ int s[256];
    int t = threadIdx.x;
    int mine = blockCnt[t];
    s[t] = mine;
    __syncthreads();
    for (int d = 1; d < 256; d <<= 1) {
        int v = (t >= d) ? s[t - d] : 0;
        __syncthreads();
        s[t] += v;
        __syncthreads();
    }
    blockOff[t] = s[t] - mine;
    if (t == 255) cnt[0] = s[255];
}

__global__ void scatter_kernel(const int* __restrict__ span_ids, const int* __restrict__ masks,
                               const int* __restrict__ flag, const int* __restrict__ pooling,
                               const int* __restrict__ blockOff,
                               int* __restrict__ cS, int* __restrict__ cE,
                               int* __restrict__ cO, int* __restrict__ cI) {
    int bid = blockIdx.x, tid = threadIdx.x;
    int m = bid * 256 + tid;
    bool act = mask_at(masks, flag[0], m);
    unsigned long long b = __ballot(act);
    __shared__ int wA[4], wI[4];
    int lane = tid & 63, w = tid >> 6;
    int wAct = __popcll(b);
    if (lane == 0) { wA[w] = wAct; wI[w] = 64 - wAct; }
    __syncthreads();
    if (tid == 0) {
        int a = 0, ii = 0;
#pragma unroll
        for (int i = 0; i < 4; ++i) {
            int ca = wA[i], ci = wI[i];
            wA[i] = a; wI[i] = ii; a += ca; ii += ci;
        }
    }
    __syncthreads();
    unsigned long long below = (lane == 63) ? ~0ULL >> 1 : ((1ULL << lane) - 1ULL);
    if (act) {
        int rank = __popcll(b & below);
        int idx = blockOff[bid] + wA[w] + rank;
        int s = span_ids[2 * m], e = span_ids[2 * m + 1];
        int bb = m >> 14;
        int window = (pooling[0] != 0) ? 1 : 3;
        int cw = min(window, e - s);
        int base = (bb * 3 + (cw - 1)) * SEQ;
        cS[idx] = base + s;
        cE[idx] = base + (e - cw);
        cO[idx] = m;
    } else {
        int rank = __popcll(~b & below);
        int idx = (bid * 256 - blockOff[bid]) + wI[w] + rank;
        cI[idx] = m;
    }
}

// ---------------------------------------------------------------------------
__global__ void prep_m3_kernel(const float* __restrict__ T, bf16* __restrict__ M3) {
    int b = blockIdx.y;
    int p0 = blockIdx.x * 16;
    int t = threadIdx.x;
    const float* Tb = T + (size_t)b * SEQ * HID;
    bf16* o0 = M3 + (size_t)(b * 3 + 0) * SEQ * HID;
    bf16* o1 = M3 + (size_t)(b * 3 + 1) * SEQ * HID;
    bf16* o2 = M3 + (size_t)(b * 3 + 2) * SEQ * HID;
#pragma unroll
    for (int c = 0; c < 3; ++c) {
        int h = t + c * 256;
        float x0 = Tb[(size_t)p0 * HID + h];
        float x1 = Tb[(size_t)min(p0 + 1, SEQ - 1) * HID + h];
        for (int i = 0; i < 16; ++i) {
            int p = p0 + i;
            float x2 = Tb[(size_t)min(p + 2, SEQ - 1) * HID + h];
            float m2 = fmaxf(x0, x1);
            float m3v = fmaxf(m2, x2);
            size_t off = (size_t)p * HID + h;
            o0[off] = __float2bfloat16(x0);
            o1[off] = __float2bfloat16(m2);
            o2[off] = __float2bfloat16(m3v);
            x0 = x1; x1 = x2;
        }
    }
}

// ---------------------------------------------------------------------------
__global__ void prep_wt_kernel(const float* __restrict__ W, bf16* __restrict__ Wt) {
    __shared__ float tile[64][65];
    int k0 = blockIdx.x * 64;
    int n0 = blockIdx.y * 64;
    int t = threadIdx.x;
    int c = t & 63, r4 = t >> 6;
    for (int r = r4; r < 64; r += 4)
        tile[r][c] = W[(size_t)(k0 + r) * HID + n0 + c];
    __syncthreads();
    for (int r = r4; r < 64; r += 4)
        Wt[(size_t)(n0 + r) * K2 + k0 + c] = __float2bfloat16(tile[c][r]);
}

// ---------------------------------------------------------------------------
// 8-phase-style 256x256 GEMM over compacted rows (m201 template geometry).
// 512 thr = 8 waves (2m x 4n), per-wave 128x64 out. BK=64; half-tiles are
// [128 rows][64 bf16 = 128 B], chunk^=row&7 swizzle (src+read, proven 0-confl).
// LDS: A = 2dbuf x 2half x 16KB @0; B same @64K. B-frags register-held per
// K-tile (read in phase 0) => staged regions provably dead when overwritten:
//   p1: stage B0(t+2)   (dead since p0)
//   p2: stage B1(t+2)   (dead since p0)
//   p3: stage A[0,64)(t+2)   (dead since p1)
//   p0: stage A[64,128)(t+1) (dead since prev tile p3)
// vmcnt: 2 issues/thread/phase; tile t's last load at (t-1)p0 => 6 newer =>
// steady vmcnt(6); last tile vmcnt(0). Prologue = 14 loads in steady order.
__global__ __launch_bounds__(512, 2)
void span_gemm_kernel(const bf16* __restrict__ M3, const bf16* __restrict__ Wt,
                      const int* __restrict__ cS, const int* __restrict__ cE,
                      const int* __restrict__ cO, const int* __restrict__ cI,
                      const int* __restrict__ cnt,
                      const float* __restrict__ bias, float* __restrict__ out) {
    __shared__ char lds[131072];
    __shared__ int rOs[256];

    const int tid = threadIdx.x;
    const int count = cnt[0];
    const int actT = (count + 255) >> 8;

    // bijective XCD remap (m204): same m-tile's 3 strips land on one XCD.
    const int q8 = NWG >> 3, r8 = NWG & 7;
    int orig = blockIdx.x;
    int xcd = orig & 7, loc = orig >> 3;
    int id = (xcd < r8 ? xcd * (q8 + 1) : r8 * (q8 + 1) + (xcd - r8) * q8) + loc;
    const int mt = id / 3, ns = id % 3;
    const int n0 = ns * 256;

    if (mt >= actT) {
        // ---- inactive fill: out[cI[r]] = bias over this 256-col strip ----
        int fr = (mt - actT) * 256 + (tid >> 1);
        if (fr < M_TOT - count) {
            int o = cI[fr];
            int c0 = n0 + (tid & 1) * 128;
            const float* bs = bias + c0;
            float* dst = out + (size_t)o * HID + c0;
#pragma unroll
            for (int c = 0; c < 32; ++c)
                *(f32x4*)(dst + c * 4) = *(const f32x4*)(bs + c * 4);
        }
        return;
    }

    const int m0 = mt * 256;
    if (tid < 256) rOs[tid] = cO[m0 + tid];

    const int lane = tid & 63, w = tid >> 6;
    const int wm = w >> 2, wn = w & 3, bh = wn >> 1;
    const int lr = lane & 15, lg = lane >> 4;
    const int wOff = w * 1024;

    // Staging: per issue (8KB = 64 rows x 128B) thread covers row tid>>3,
    // chunk tid&7, source chunk pre-swizzled by row&7.
    const int swz = ((tid & 7) ^ ((tid >> 3) & 7)) << 4;
    const char* aSp[4]; const char* aEp[4]; const char* bPp[4];
#pragma unroll
    for (int j = 0; j < 4; ++j) {
        int rr = m0 + j * 64 + (tid >> 3);
        aSp[j] = (const char*)M3 + (size_t)cS[rr] * 1536 + swz;
        aEp[j] = (const char*)M3 + (size_t)cE[rr] * 1536 + swz;
        bPp[j] = (const char*)Wt + (size_t)(n0 + j * 64 + (tid >> 3)) * 3072 + swz;
    }
    char* const Abase = lds;
    char* const Bbase = lds + 65536;

#define ST_A(T, HALF, RB) gll16((((T) < 12) ? aSp : aEp)[(HALF) * 2 + ((RB) >> 6)] \
            + (((T) < 12 ? (T) : (T) - 12) * 128), \
        Abase + (((T) & 1) * 32768) + (HALF) * 16384 + (RB) * 128 + wOff)
#define ST_B(T, Q) gll16(bPp[Q] + (T) * 128, \
        Bbase + (((T) & 1) * 32768) + (Q) * 8192 + wOff)
#define BAR() do { __builtin_amdgcn_sched_barrier(0); \
        asm volatile("" ::: "memory"); \
        __builtin_amdgcn_s_barrier(); \
        asm volatile("" ::: "memory"); \
        __builtin_amdgcn_sched_barrier(0); } while (0)
#define COMPUTE2(P) do { \
        const int _r0 = (2 * (P)) * 16 + lr, _r1 = (2 * (P) + 1) * 16 + lr; \
        s16x8 _a0[2], _a1[2]; \
        _Pragma("unroll") \
        for (int _ks = 0; _ks < 2; ++_ks) { \
            _a0[_ks] = *(const s16x8*)(Ar + _r0 * 128 + ((((_ks << 2) | lg) ^ (_r0 & 7)) << 4)); \
            _a1[_ks] = *(const s16x8*)(Ar + _r1 * 128 + ((((_ks << 2) | lg) ^ (_r1 & 7)) << 4)); \
        } \
        __builtin_amdgcn_s_setprio(1); \
        _Pragma("unroll") \
        for (int _ks = 0; _ks < 2; ++_ks) { \
            _Pragma("unroll") \
            for (int _nf = 0; _nf < 4; ++_nf) { \
                acc[2 * (P)][_nf] = __builtin_amdgcn_mfma_f32_16x16x32_bf16(_a0[_ks], bfr[_nf][_ks], acc[2 * (P)][_nf], 0, 0, 0); \
                acc[2 * (P) + 1][_nf] = __builtin_amdgcn_mfma_f32_16x16x32_bf16(_a1[_ks], bfr[_nf][_ks], acc[2 * (P) + 1][_nf], 0, 0, 0); \
            } \
        } \
        __builtin_amdgcn_s_setprio(0); \
    } while (0)

    f32x4 acc[8][4];
#pragma unroll
    for (int i = 0; i < 8; i++)
#pragma unroll
        for (int j = 0; j < 4; j++) acc[i][j] = (f32x4){0.f, 0.f, 0.f, 0.f};

    // Prologue: tile0 full (8), tile1 B+A-low (6) -> 14 in flight.
    ST_B(0, 0); ST_B(0, 1); ST_B(0, 2); ST_B(0, 3);
    ST_A(0, 0, 0); ST_A(0, 1, 0);
    ST_A(0, 0, 64); ST_A(0, 1, 64);
    ST_B(1, 0); ST_B(1, 1); ST_B(1, 2); ST_B(1, 3);
    ST_A(1, 0, 0); ST_A(1, 1, 0);

    for (int t = 0; t < NTILE; ++t) {
        const int db = t & 1;
        const char* Ar = Abase + db * 32768 + wm * 16384;
        const char* Br = Bbase + db * 32768 + bh * 16384;
        s16x8 bfr[4][2];

        // ---- phase 0 ----
        if (t < NTILE - 1) { asm volatile("s_waitcnt vmcnt(6)" ::: "memory"); }
        else               { asm volatile("s_waitcnt vmcnt(0)" ::: "memory"); }
        BAR();
        if (t + 1 < NTILE) { ST_A(t + 1, 0, 64); ST_A(t + 1, 1, 64); }
#pragma unroll
        for (int nf = 0; nf < 4; ++nf) {
            const int lc = (wn & 1) * 64 + nf * 16 + lr;
#pragma unroll
            for (int ks = 0; ks < 2; ++ks)
                bfr[nf][ks] = *(const s16x8*)(Br + lc * 128 + ((((ks << 2) | lg) ^ (lc & 7)) << 4));
        }
        COMPUTE2(0);
        // ---- phase 1 ----
        BAR();
        if (t + 2 < NTILE) { ST_B(t + 2, 0); ST_B(t + 2, 1); }
        COMPUTE2(1);
        // ---- phase 2 ----
        BAR();
        if (t + 2 < NTILE) { ST_B(t + 2, 2); ST_B(t + 2, 3); }
        COMPUTE2(2);
        // ---- phase 3 ----
        BAR();
        if (t + 2 < NTILE) { ST_A(t + 2, 0, 0); ST_A(t + 2, 1, 0); }
        COMPUTE2(3);
    }
#undef ST_A
#undef ST_B
#undef BAR
#undef COMPUTE2

    // Epilogue: C/D layout (verified m89): col = lane&15, row = (lane>>4)*4+q
#pragma unroll
    for (int mf = 0; mf < 8; ++mf) {
#pragma unroll
        for (int nf = 0; nf < 4; ++nf) {
#pragma unroll
            for (int qq = 0; qq < 4; ++qq) {
                int mloc = wm * 128 + mf * 16 + lg * 4 + qq;
                int o = rOs[mloc];
                if (o >= 0) {
                    int n = n0 + wn * 64 + nf * 16 + lr;
                    out[(size_t)o * HID + n] = acc[mf][nf][qq] + bias[n];
                }
            }
        }
    }
}

// ---------------------------------------------------------------------------
extern "C" void kernel_launch(void* const* d_in, const int* in_sizes, int n_in,
                              void* d_out, int out_size, void* d_ws, size_t ws_size,
                              hipStream_t stream) {
    const float* token_reps = (const float*)d_in[0];
    const int*   span_ids   = (const int*)d_in[1];
    const int*   span_masks = (const int*)d_in[2];
    const int*   pooling    = (const int*)d_in[3];
    const float* W          = (const float*)d_in[4];
    const float* bias       = (const float*)d_in[5];
    float* out = (float*)d_out;

    char* ws = (char*)d_ws;
    int*  flag = (int*)ws;
    int*  cnt  = (int*)(ws + 4);
    int*  blockCnt = (int*)(ws + 1024);
    int*  blockOff = (int*)(ws + 2048);
    int*  cS   = (int*)(ws + 4096);
    int*  cE   = (int*)(ws + 4096 + 4 * CMP_CAP);
    int*  cO   = (int*)(ws + 4096 + 8 * CMP_CAP);
    int*  cI   = (int*)(ws + 4096 + 12 * CMP_CAP);
    bf16* M3   = (bf16*)(ws + (2 << 20));
    const size_t M3_BYTES = (size_t)NB * 3 * SEQ * HID * 2;   // 37,748,736
    bf16* Wt   = (bf16*)(ws + (2 << 20) + M3_BYTES);

    hipMemsetAsync(ws, 0, 64, stream);
    mask_detect_kernel<<<64, 256, 0, stream>>>((const unsigned*)span_masks, flag);
    init_compact_kernel<<<(CMP_CAP + 255) / 256, 256, 0, stream>>>(cS, cE, cO);
    count_kernel<<<M_TOT / 256, 256, 0, stream>>>(span_masks, flag, blockCnt);
    scan_kernel<<<1, 256, 0, stream>>>(blockCnt, blockOff, cnt);
    scatter_kernel<<<M_TOT / 256, 256, 0, stream>>>(span_ids, span_masks, flag, pooling,
                                                    blockOff, cS, cE, cO, cI);
    prep_m3_kernel<<<dim3(SEQ / 16, NB), 256, 0, stream>>>(token_reps, M3);
    prep_wt_kernel<<<dim3(K2 / 64, HID / 64), 256, 0, stream>>>(W, Wt);
    span_gemm_kernel<<<NWG, 512, 0, stream>>>(
        M3, Wt, cS, cE, cO, cI, cnt, bias, out);
}

// Round 8
// 188.443 us; speedup vs baseline: 2.0241x; 2.0241x over previous
//
#include <hip/hip_runtime.h>
#include <hip/hip_bf16.h>

// Problem constants (fixed by setup_inputs)
#define NB 4
#define SEQ 2048
#define HID 768
#define NSPAN 16384            // spans per batch
#define M_TOT (NB * NSPAN)     // 65536 rows
#define K2 1536                // 2*HID
#define CMP_CAP 66560          // compacted-table capacity = 520*128
#define MT_TOT 520             // m-tile id space (multiple of 8, >= 512+fill)
#define NWG (MT_TOT * 6)       // 3120 blocks, 1D grid

typedef float f32x4 __attribute__((ext_vector_type(4)));
typedef short s16x8 __attribute__((ext_vector_type(8)));
using bf16 = __hip_bfloat16;

// global -> LDS direct (16B per lane). LDS dest is wave-uniform base + lane*16;
// global src is per-lane (gather-capable).
__device__ __forceinline__ void gll16(const void* g, void* l) {
    __builtin_amdgcn_global_load_lds(
        (const __attribute__((address_space(1))) unsigned*)g,
        (__attribute__((address_space(3))) unsigned*)l, 16, 0, 0);
}

// ---------------------------------------------------------------------------
// Detect span_masks dtype: int32 words (0/1) vs byte-packed bools.
__global__ void mask_detect_kernel(const unsigned* __restrict__ masks, int* __restrict__ flag) {
    int t = blockIdx.x * 256 + threadIdx.x;
    if (t < 16384) {
        unsigned v = masks[t];
        if (v > 1u) atomicOr(flag, 1);   // multi-byte pattern => byte-packed bools
    }
}

__device__ __forceinline__ bool mask_at(const int* masks, int u8, int m) {
    return u8 ? (((const unsigned char*)masks)[m] != 0) : (masks[m] != 0);
}

// ---------------------------------------------------------------------------
// Default-fill compacted tables (pad rows: gather M3 row 0, no output store).
__global__ void init_compact_kernel(int* __restrict__ cS, int* __restrict__ cE,
                                    int* __restrict__ cO) {
    int i = blockIdx.x * 256 + threadIdx.x;
    if (i < CMP_CAP) { cS[i] = 0; cE[i] = 0; cO[i] = -1; }
}

// ---------------------------------------------------------------------------
// Order-preserving compaction, pass 1: per-256-span block active count.
__global__ void count_kernel(const int* __restrict__ masks, const int* __restrict__ flag,
                             int* __restrict__ blockCnt) {
    int bid = blockIdx.x, tid = threadIdx.x;
    bool act = mask_at(masks, flag[0], bid * 256 + tid);
    unsigned long long b = __ballot(act);
    __shared__ int wc[4];
    if ((tid & 63) == 0) wc[tid >> 6] = __popcll(b);
    __syncthreads();
    if (tid == 0) blockCnt[bid] = wc[0] + wc[1] + wc[2] + wc[3];
}

// Pass 2: exclusive scan over the 256 block counts (single block).
__global__ void scan_kernel(const int* __restrict__ blockCnt, int* __restrict__ blockOff,
                            int* __restrict__ cnt) {
    __shared__ int s[256];
    int t = threadIdx.x;
    int mine = blockCnt[t];
    s[t] = mine;
    __syncthreads();
    for (int d = 1; d < 256; d <<= 1) {
        int v = (t >= d) ? s[t - d] : 0;
        __syncthreads();
        s[t] += v;
        __syncthreads();
    }
    blockOff[t] = s[t] - mine;          // exclusive prefix
    if (t == 255) cnt[0] = s[255];
}

// Pass 3: rank-scatter, order-preserving for BOTH active (cS/cE/cO) and
// inactive (cI) rows. Preserved order => batch-slab L2/L3 locality in GEMM.
__global__ void scatter_kernel(const int* __restrict__ span_ids, const int* __restrict__ masks,
                               const int* __restrict__ flag, const int* __restrict__ pooling,
                               const int* __restrict__ blockOff,
                               int* __restrict__ cS, int* __restrict__ cE,
                               int* __restrict__ cO, int* __restrict__ cI) {
    int bid = blockIdx.x, tid = threadIdx.x;
    int m = bid * 256 + tid;
    bool act = mask_at(masks, flag[0], m);
    unsigned long long b = __ballot(act);
    __shared__ int wA[4], wI[4];
    int lane = tid & 63, w = tid >> 6;
    int wAct = __popcll(b);
    if (lane == 0) { wA[w] = wAct; wI[w] = 64 - wAct; }
    __syncthreads();
    if (tid == 0) {
        int a = 0, ii = 0;
#pragma unroll
        for (int i = 0; i < 4; ++i) {
            int ca = wA[i], ci = wI[i];
            wA[i] = a; wI[i] = ii; a += ca; ii += ci;
        }
    }
    __syncthreads();
    unsigned long long below = (lane == 63) ? ~0ULL >> 1 : ((1ULL << lane) - 1ULL);
    if (act) {
        int rank = __popcll(b & below);
        int idx = blockOff[bid] + wA[w] + rank;
        int s = span_ids[2 * m], e = span_ids[2 * m + 1];
        int bb = m >> 14;                      // m / NSPAN
        int window = (pooling[0] != 0) ? 1 : 3;
        int cw = min(window, e - s);           // e-s >= 1 always
        int base = (bb * 3 + (cw - 1)) * SEQ;
        cS[idx] = base + s;
        cE[idx] = base + (e - cw);
        cO[idx] = m;
    } else {
        int rank = __popcll(~b & below);
        int idx = (bid * 256 - blockOff[bid]) + wI[w] + rank;
        cI[idx] = m;
    }
}

// ---------------------------------------------------------------------------
// M3[b][c][p][h] = max over T[b, p .. p+c] (c = 0,1,2 => window 1,2,3), bf16.
__global__ void prep_m3_kernel(const float* __restrict__ T, bf16* __restrict__ M3) {
    int b = blockIdx.y;
    int p0 = blockIdx.x * 16;
    int t = threadIdx.x;   // 256
    const float* Tb = T + (size_t)b * SEQ * HID;
    bf16* o0 = M3 + (size_t)(b * 3 + 0) * SEQ * HID;
    bf16* o1 = M3 + (size_t)(b * 3 + 1) * SEQ * HID;
    bf16* o2 = M3 + (size_t)(b * 3 + 2) * SEQ * HID;
#pragma unroll
    for (int c = 0; c < 3; ++c) {
        int h = t + c * 256;
        float x0 = Tb[(size_t)p0 * HID + h];
        float x1 = Tb[(size_t)min(p0 + 1, SEQ - 1) * HID + h];
        for (int i = 0; i < 16; ++i) {
            int p = p0 + i;
            float x2 = Tb[(size_t)min(p + 2, SEQ - 1) * HID + h];
            float m2 = fmaxf(x0, x1);
            float m3v = fmaxf(m2, x2);
            size_t off = (size_t)p * HID + h;
            o0[off] = __float2bfloat16(x0);
            o1[off] = __float2bfloat16(m2);
            o2[off] = __float2bfloat16(m3v);
            x0 = x1; x1 = x2;
        }
    }
}

// ---------------------------------------------------------------------------
// Wt[n][k] = bf16(W[k][n]); W is (K2, HID) f32 row-major. 64x64 LDS transpose.
__global__ void prep_wt_kernel(const float* __restrict__ W, bf16* __restrict__ Wt) {
    __shared__ float tile[64][65];
    int k0 = blockIdx.x * 64;
    int n0 = blockIdx.y * 64;
    int t = threadIdx.x;
    int c = t & 63, r4 = t >> 6;
    for (int r = r4; r < 64; r += 4)
        tile[r][c] = W[(size_t)(k0 + r) * HID + n0 + c];
    __syncthreads();
    for (int r = r4; r < 64; r += 4)
        Wt[(size_t)(n0 + r) * K2 + k0 + c] = __float2bfloat16(tile[c][r]);
}

// ---------------------------------------------------------------------------
// GEMM over compacted ACTIVE rows — R5's proven single-buffer structure
// (32KB LDS, 2-barrier loop, 128x128 tile, 4 waves) with a balanced XCD
// co-location swizzle:
//   x = blockIdx.x (1D, 3120);  g = x & 7 (XCD, x%8 round-robin assumption)
//   j = x >> 3;  mt = (j/6)*8 + g;  ns = j%6
// => all 6 n-strips of one m-tile land on ONE XCD (A gather rows become
// L2-resident after the first strip), heavy m-tiles round-robin across XCDs
// (fixes R7's imbalance). Blocks past the active tile count fill bias rows.
__global__ __launch_bounds__(256, 4)
void span_gemm_kernel(const bf16* __restrict__ M3, const bf16* __restrict__ Wt,
                      const int* __restrict__ cS, const int* __restrict__ cE,
                      const int* __restrict__ cO, const int* __restrict__ cI,
                      const int* __restrict__ cnt,
                      const float* __restrict__ bias, float* __restrict__ out) {
    __shared__ char lA[128 * 128];   // 16 KB
    __shared__ char lB[128 * 128];   // 16 KB
    __shared__ int rS[128], rE[128], rO[128];

    const int tid = threadIdx.x;
    const int x = blockIdx.x;
    const int g = x & 7, j = x >> 3;
    const int mt = (j / 6) * 8 + g;    // m-tile, round-robin over XCDs
    const int ns = j % 6;              // n-strip, co-located with its m-tile
    const int n0 = ns * 128;

    const int count = cnt[0];
    const int actT = (count + 127) >> 7;

    if (mt >= actT) {
        // ---- inactive fill: out[cI[r]][n0..n0+128) = bias[n0..n0+128) ----
        int r = (mt - actT) * 128 + (tid >> 1);
        if (r < M_TOT - count) {
            int o = cI[r];
            const float* bsrc = bias + n0 + (tid & 1) * 64;
            float* dst = out + (size_t)o * HID + n0 + (tid & 1) * 64;
#pragma unroll
            for (int c = 0; c < 16; ++c)
                *(f32x4*)(dst + c * 4) = *(const f32x4*)(bsrc + c * 4);
        }
        return;
    }

    const int m0 = mt * 128;

    if (tid < 128) {
        int m = m0 + tid;
        rS[tid] = cS[m];
        rE[tid] = cE[m];
        rO[tid] = cO[m];
    }
    __syncthreads();

    const int lane = tid & 63, w = tid >> 6;
    const int wr = w >> 1, wc = w & 1;        // wave 2x2 over the 128x128 tile
    const int lr = lane & 15, lg = lane >> 4;

    // Staging geometry: per K-step each operand is 128 rows x 128 B = 8KB
    // = 8 wave-issues of 1KB; 4 issues per thread per operand.
    const int lrow8 = lane >> 3;
    const int chunkp = ((lane & 7) ^ lrow8) << 4;   // swizzled byte offset in row

    const char* aPtr[2][4];
    const char* bPtr[4];
    int ldsOff[4];
#pragma unroll
    for (int it = 0; it < 4; ++it) {
        int i = it * 4 + w;                    // 1KB-issue index 0..31
        int r = i * 8 + lrow8;                 // LDS row 0..127
        aPtr[0][it] = (const char*)M3 + (size_t)rS[r] * (HID * 2) + chunkp;
        aPtr[1][it] = (const char*)M3 + (size_t)rE[r] * (HID * 2) + chunkp;
        bPtr[it]    = (const char*)Wt + (size_t)(n0 + r) * (K2 * 2) + chunkp;
        ldsOff[it]  = i * 1024;                // wave-uniform dest
    }

    f32x4 acc[4][4];
#pragma unroll
    for (int i = 0; i < 4; i++)
#pragma unroll
        for (int j2 = 0; j2 < 4; j2++) acc[i][j2] = (f32x4){0.f, 0.f, 0.f, 0.f};

    for (int kt = 0; kt < K2; kt += 64) {
        const int half = (kt >= HID) ? 1 : 0;
        const int colB = (kt - (half ? HID : 0)) * 2;   // byte col within M3 row
        const int ktB  = kt * 2;                        // byte col within Wt row
        __syncthreads();   // previous tile fully consumed by all waves
#pragma unroll
        for (int it = 0; it < 4; ++it)
            gll16(aPtr[half][it] + colB, lA + ldsOff[it]);
#pragma unroll
        for (int it = 0; it < 4; ++it)
            gll16(bPtr[it] + ktB, lB + ldsOff[it]);
        __syncthreads();   // vmcnt(0) drained by compiler before barrier
#pragma unroll
        for (int kk = 0; kk < 2; ++kk) {
            const int cb = kk * 4 + lg;        // global 16B-chunk index (k/8)
            s16x8 af[4], bfr[4];
#pragma unroll
            for (int i = 0; i < 4; ++i) {
                int row = wr * 64 + i * 16 + lr;
                af[i] = *(const s16x8*)(lA + row * 128 + ((cb ^ (row & 7)) << 4));
            }
#pragma unroll
            for (int j2 = 0; j2 < 4; ++j2) {
                int row = wc * 64 + j2 * 16 + lr;
                bfr[j2] = *(const s16x8*)(lB + row * 128 + ((cb ^ (row & 7)) << 4));
            }
#pragma unroll
            for (int i = 0; i < 4; ++i)
#pragma unroll
                for (int j2 = 0; j2 < 4; ++j2)
                    acc[i][j2] = __builtin_amdgcn_mfma_f32_16x16x32_bf16(af[i], bfr[j2], acc[i][j2], 0, 0, 0);
        }
    }

    // Epilogue: C/D layout (verified m89): col = lane&15, row = (lane>>4)*4 + q
#pragma unroll
    for (int i = 0; i < 4; i++) {
#pragma unroll
        for (int j2 = 0; j2 < 4; j2++) {
#pragma unroll
            for (int q = 0; q < 4; q++) {
                int mloc = wr * 64 + i * 16 + lg * 4 + q;
                int o = rO[mloc];
                if (o >= 0) {
                    int n = n0 + wc * 64 + j2 * 16 + lr;
                    out[(size_t)o * HID + n] = acc[i][j2][q] + bias[n];
                }
            }
        }
    }
}

// ---------------------------------------------------------------------------
extern "C" void kernel_launch(void* const* d_in, const int* in_sizes, int n_in,
                              void* d_out, int out_size, void* d_ws, size_t ws_size,
                              hipStream_t stream) {
    const float* token_reps = (const float*)d_in[0];
    const int*   span_ids   = (const int*)d_in[1];
    const int*   span_masks = (const int*)d_in[2];
    const int*   pooling    = (const int*)d_in[3];
    const float* W          = (const float*)d_in[4];
    const float* bias       = (const float*)d_in[5];
    float* out = (float*)d_out;

    // ws layout:
    //   [0,4) flag | [4,8) cnt | [1024,+1KB) blockCnt | [2048,+1KB) blockOff
    //   [4096) cS | cE | cO (CMP_CAP ints each) | cI (M_TOT ints)
    //   [2MB, +37.75MB) M3 | then Wt (2.25MB)
    char* ws = (char*)d_ws;
    int*  flag = (int*)ws;
    int*  cnt  = (int*)(ws + 4);
    int*  blockCnt = (int*)(ws + 1024);
    int*  blockOff = (int*)(ws + 2048);
    int*  cS   = (int*)(ws + 4096);
    int*  cE   = (int*)(ws + 4096 + 4 * (size_t)CMP_CAP);
    int*  cO   = (int*)(ws + 4096 + 8 * (size_t)CMP_CAP);
    int*  cI   = (int*)(ws + 4096 + 12 * (size_t)CMP_CAP);
    bf16* M3   = (bf16*)(ws + (2 << 20));
    const size_t M3_BYTES = (size_t)NB * 3 * SEQ * HID * 2;   // 37,748,736
    bf16* Wt   = (bf16*)(ws + (2 << 20) + M3_BYTES);

    hipMemsetAsync(ws, 0, 64, stream);
    mask_detect_kernel<<<64, 256, 0, stream>>>((const unsigned*)span_masks, flag);
    init_compact_kernel<<<(CMP_CAP + 255) / 256, 256, 0, stream>>>(cS, cE, cO);
    count_kernel<<<M_TOT / 256, 256, 0, stream>>>(span_masks, flag, blockCnt);
    scan_kernel<<<1, 256, 0, stream>>>(blockCnt, blockOff, cnt);
    scatter_kernel<<<M_TOT / 256, 256, 0, stream>>>(span_ids, span_masks, flag, pooling,
                                                    blockOff, cS, cE, cO, cI);
    prep_m3_kernel<<<dim3(SEQ / 16, NB), 256, 0, stream>>>(token_reps, M3);
    prep_wt_kernel<<<dim3(K2 / 64, HID / 64), 256, 0, stream>>>(W, Wt);
    span_gemm_kernel<<<NWG, 256, 0, stream>>>(
        M3, Wt, cS, cE, cO, cI, cnt, bias, out);
}

// Round 9
// 149.675 us; speedup vs baseline: 2.5484x; 1.2590x over previous
//
#include <hip/hip_runtime.h>
#include <hip/hip_bf16.h>

// Problem constants (fixed by setup_inputs)
#define NB 4
#define SEQ 2048
#define HID 768
#define NSPAN 16384            // spans per batch
#define M_TOT (NB * NSPAN)     // 65536 rows
#define K2 1536                // 2*HID
#define MROWS (NB * 3 * SEQ)   // 24576 table rows (batch x width-class x pos)
// old (fallback) path constants
#define CMP_CAP 66560
#define MT_TOT 520
#define NWG_OLD (MT_TOT * 6)
// new path GEMM grid: 192 m-tiles x 12 n-strips
#define NWG_NEW 2304

typedef float f32x4 __attribute__((ext_vector_type(4)));
typedef short s16x8 __attribute__((ext_vector_type(8)));
typedef unsigned short u16x4 __attribute__((ext_vector_type(4)));
using bf16 = __hip_bfloat16;

__device__ __forceinline__ void gll16(const void* g, void* l) {
    __builtin_amdgcn_global_load_lds(
        (const __attribute__((address_space(1))) unsigned*)g,
        (__attribute__((address_space(3))) unsigned*)l, 16, 0, 0);
}

__device__ __forceinline__ float bf2f(unsigned short v) {
    union { unsigned u; float f; } cv; cv.u = ((unsigned)v) << 16; return cv.f;
}

// ---------------------------------------------------------------------------
__global__ void mask_detect_kernel(const unsigned* __restrict__ masks, int* __restrict__ flag) {
    int t = blockIdx.x * 256 + threadIdx.x;
    if (t < 16384) {
        unsigned v = masks[t];
        if (v > 1u) atomicOr(flag, 1);   // multi-byte pattern => byte-packed bools
    }
}

__device__ __forceinline__ bool mask_at(const int* masks, int u8, int m) {
    return u8 ? (((const unsigned char*)masks)[m] != 0) : (masks[m] != 0);
}

// ---------------------------------------------------------------------------
// M3[b][c][p][h] = max over T[b, p .. p+c] (c = 0,1,2 => window 1,2,3), bf16.
__global__ void prep_m3_kernel(const float* __restrict__ T, bf16* __restrict__ M3) {
    int b = blockIdx.y;
    int p0 = blockIdx.x * 16;
    int t = threadIdx.x;   // 256
    const float* Tb = T + (size_t)b * SEQ * HID;
    bf16* o0 = M3 + (size_t)(b * 3 + 0) * SEQ * HID;
    bf16* o1 = M3 + (size_t)(b * 3 + 1) * SEQ * HID;
    bf16* o2 = M3 + (size_t)(b * 3 + 2) * SEQ * HID;
#pragma unroll
    for (int c = 0; c < 3; ++c) {
        int h = t + c * 256;
        float x0 = Tb[(size_t)p0 * HID + h];
        float x1 = Tb[(size_t)min(p0 + 1, SEQ - 1) * HID + h];
        for (int i = 0; i < 16; ++i) {
            int p = p0 + i;
            float x2 = Tb[(size_t)min(p + 2, SEQ - 1) * HID + h];
            float m2 = fmaxf(x0, x1);
            float m3v = fmaxf(m2, x2);
            size_t off = (size_t)p * HID + h;
            o0[off] = __float2bfloat16(x0);
            o1[off] = __float2bfloat16(m2);
            o2[off] = __float2bfloat16(m3v);
            x0 = x1; x1 = x2;
        }
    }
}

// ===========================================================================
// NEW PATH: dense table GEMM + gather-add epilogue
// ===========================================================================

// Wt2[n'][k'] (n' 0..1535, k' 0..767):
//   n'<768:  W[k'][n']         (start half, W rows 0..767)
//   n'>=768: W[768+k'][n'-768] (end half,  W rows 768..1535)
__global__ void prep_wt2_kernel(const float* __restrict__ W, bf16* __restrict__ Wt) {
    __shared__ float tile[64][65];
    int k0 = blockIdx.x * 64;          // 12 blocks
    int n0 = blockIdx.y * 64;          // 24 blocks
    int half = (n0 >= HID) ? 1 : 0;
    int nn = n0 - half * HID;
    int t = threadIdx.x;
    int c = t & 63, r4 = t >> 6;
    for (int r = r4; r < 64; r += 4)
        tile[r][c] = W[(size_t)(half * HID + k0 + r) * HID + nn + c];
    __syncthreads();
    for (int r = r4; r < 64; r += 4)
        Wt[(size_t)(n0 + r) * HID + k0 + c] = __float2bfloat16(tile[c][r]);
}

// Dense GEMM: P[r][n'] = sum_k M3[r][k] * Wt2[n'][k], r<24576, n'<1536.
// R5/R8's proven 2-barrier 128x128 structure; A rows are SEQUENTIAL (no
// gather). chunk^=row&7 swizzle on source AND read (measured 0 conflicts).
// XCD co-location: all 12 n-strips of one m-tile on one XCD, m-tiles
// round-robin across XCDs (balanced, bijective).
__global__ __launch_bounds__(256, 4)
void dense_gemm_kernel(const bf16* __restrict__ M3, const bf16* __restrict__ Wt,
                       bf16* __restrict__ P) {
    __shared__ char lA[16384];
    __shared__ char lB[16384];

    const int tid = threadIdx.x;
    const int x = blockIdx.x;
    const int g = x & 7, j = x >> 3;
    const int mt = (j / 12) * 8 + g;   // 0..191
    const int ns = j % 12;             // 0..11
    const int m0 = mt * 128, n0 = ns * 128;

    const int lane = tid & 63, w = tid >> 6;
    const int wr = w >> 1, wc = w & 1;
    const int lr = lane & 15, lg = lane >> 4;
    const int lrow8 = lane >> 3;
    const int chunkp = ((lane & 7) ^ lrow8) << 4;

    const char* aPtr[4];
    const char* bPtr[4];
    int ldsOff[4];
#pragma unroll
    for (int it = 0; it < 4; ++it) {
        int i = it * 4 + w;                    // 1KB-issue index 0..15
        int r = i * 8 + lrow8;                 // LDS row 0..127
        aPtr[it] = (const char*)M3 + (size_t)(m0 + r) * (HID * 2) + chunkp;
        bPtr[it] = (const char*)Wt + (size_t)(n0 + r) * (HID * 2) + chunkp;
        ldsOff[it] = i * 1024;
    }

    f32x4 acc[4][4];
#pragma unroll
    for (int i = 0; i < 4; i++)
#pragma unroll
        for (int j2 = 0; j2 < 4; j2++) acc[i][j2] = (f32x4){0.f, 0.f, 0.f, 0.f};

    for (int kt = 0; kt < HID; kt += 64) {
        const int colB = kt * 2;
        __syncthreads();
#pragma unroll
        for (int it = 0; it < 4; ++it)
            gll16(aPtr[it] + colB, lA + ldsOff[it]);
#pragma unroll
        for (int it = 0; it < 4; ++it)
            gll16(bPtr[it] + colB, lB + ldsOff[it]);
        __syncthreads();
#pragma unroll
        for (int kk = 0; kk < 2; ++kk) {
            const int cb = kk * 4 + lg;
            s16x8 af[4], bfr[4];
#pragma unroll
            for (int i = 0; i < 4; ++i) {
                int row = wr * 64 + i * 16 + lr;
                af[i] = *(const s16x8*)(lA + row * 128 + ((cb ^ (row & 7)) << 4));
            }
#pragma unroll
            for (int j2 = 0; j2 < 4; ++j2) {
                int row = wc * 64 + j2 * 16 + lr;
                bfr[j2] = *(const s16x8*)(lB + row * 128 + ((cb ^ (row & 7)) << 4));
            }
#pragma unroll
            for (int i = 0; i < 4; ++i)
#pragma unroll
                for (int j2 = 0; j2 < 4; ++j2)
                    acc[i][j2] = __builtin_amdgcn_mfma_f32_16x16x32_bf16(af[i], bfr[j2], acc[i][j2], 0, 0, 0);
        }
    }

    // C/D layout (verified m89): col = lane&15, row = (lane>>4)*4 + q
    unsigned short* Pu = (unsigned short*)P;
#pragma unroll
    for (int i = 0; i < 4; i++) {
#pragma unroll
        for (int j2 = 0; j2 < 4; j2++) {
#pragma unroll
            for (int q = 0; q < 4; q++) {
                int prow = m0 + wr * 64 + i * 16 + lg * 4 + q;
                int pcol = n0 + wc * 64 + j2 * 16 + lr;
                bf16 v = __float2bfloat16(acc[i][j2][q]);
                Pu[(size_t)prow * K2 + pcol] = *(unsigned short*)&v;
            }
        }
    }
}

// out[m] = mask ? P[rS][0:768] + P[rE][768:1536] + bias : bias
// One wave per row; 3 rounds of (lane x 4 els): 8B bf16 loads, 16B f32 store.
__global__ __launch_bounds__(256)
void epilogue_kernel(const bf16* __restrict__ P, const int* __restrict__ span_ids,
                     const int* __restrict__ masks, const int* __restrict__ flag,
                     const int* __restrict__ pooling, const float* __restrict__ bias,
                     float* __restrict__ out) {
    int gw = (blockIdx.x * 256 + threadIdx.x) >> 6;   // 0..8191
    int lane = threadIdx.x & 63;
    int u8 = flag[0];
    int window = (pooling[0] != 0) ? 1 : 3;
    const unsigned short* Pu = (const unsigned short*)P;
    for (int m = gw; m < M_TOT; m += 8192) {
        float* orow = out + (size_t)m * HID;
        if (!mask_at(masks, u8, m)) {
#pragma unroll
            for (int rnd = 0; rnd < 3; ++rnd) {
                int n = rnd * 256 + lane * 4;
                *(f32x4*)(orow + n) = *(const f32x4*)(bias + n);
            }
            continue;
        }
        int s = span_ids[2 * m], e = span_ids[2 * m + 1];
        int b = m >> 14;
        int cw = min(window, e - s);           // e-s >= 1 always
        int base = (b * 3 + (cw - 1)) * SEQ;
        const unsigned short* ps = Pu + (size_t)(base + s) * K2;
        const unsigned short* pe = Pu + (size_t)(base + e - cw) * K2 + HID;
#pragma unroll
        for (int rnd = 0; rnd < 3; ++rnd) {
            int n = rnd * 256 + lane * 4;
            u16x4 a = *(const u16x4*)(ps + n);
            u16x4 c = *(const u16x4*)(pe + n);
            f32x4 bb = *(const f32x4*)(bias + n);
            f32x4 r;
#pragma unroll
            for (int k = 0; k < 4; ++k) r[k] = bf2f(a[k]) + bf2f(c[k]) + bb[k];
            *(f32x4*)(orow + n) = r;
        }
    }
}

// ===========================================================================
// OLD PATH (fallback if ws_size too small): R8's compacted gathered GEMM
// ===========================================================================

__global__ void init_compact_kernel(int* __restrict__ cS, int* __restrict__ cE,
                                    int* __restrict__ cO) {
    int i = blockIdx.x * 256 + threadIdx.x;
    if (i < CMP_CAP) { cS[i] = 0; cE[i] = 0; cO[i] = -1; }
}

__global__ void count_kernel(const int* __restrict__ masks, const int* __restrict__ flag,
                             int* __restrict__ blockCnt) {
    int bid = blockIdx.x, tid = threadIdx.x;
    bool act = mask_at(masks, flag[0], bid * 256 + tid);
    unsigned long long b = __ballot(act);
    __shared__ int wc[4];
    if ((tid & 63) == 0) wc[tid >> 6] = __popcll(b);
    __syncthreads();
    if (tid == 0) blockCnt[bid] = wc[0] + wc[1] + wc[2] + wc[3];
}

__global__ void scan_kernel(const int* __restrict__ blockCnt, int* __restrict__ blockOff,
                            int* __restrict__ cnt) {
    __shared__ int s[256];
    int t = threadIdx.x;
    int mine = blockCnt[t];
    s[t] = mine;
    __syncthreads();
    for (int d = 1; d < 256; d <<= 1) {
        int v = (t >= d) ? s[t - d] : 0;
        __syncthreads();
        s[t] += v;
        __syncthreads();
    }
    blockOff[t] = s[t] - mine;
    if (t == 255) cnt[0] = s[255];
}

__global__ void scatter_kernel(const int* __restrict__ span_ids, const int* __restrict__ masks,
                               const int* __restrict__ flag, const int* __restrict__ pooling,
                               const int* __restrict__ blockOff,
                               int* __restrict__ cS, int* __restrict__ cE,
                               int* __restrict__ cO, int* __restrict__ cI) {
    int bid = blockIdx.x, tid = threadIdx.x;
    int m = bid * 256 + tid;
    bool act = mask_at(masks, flag[0], m);
    unsigned long long b = __ballot(act);
    __shared__ int wA[4], wI[4];
    int lane = tid & 63, w = tid >> 6;
    int wAct = __popcll(b);
    if (lane == 0) { wA[w] = wAct; wI[w] = 64 - wAct; }
    __syncthreads();
    if (tid == 0) {
        int a = 0, ii = 0;
#pragma unroll
        for (int i = 0; i < 4; ++i) {
            int ca = wA[i], ci = wI[i];
            wA[i] = a; wI[i] = ii; a += ca; ii += ci;
        }
    }
    __syncthreads();
    unsigned long long below = (lane == 63) ? ~0ULL >> 1 : ((1ULL << lane) - 1ULL);
    if (act) {
        int rank = __popcll(b & below);
        int idx = blockOff[bid] + wA[w] + rank;
        int s = span_ids[2 * m], e = span_ids[2 * m + 1];
        int bb = m >> 14;
        int window = (pooling[0] != 0) ? 1 : 3;
        int cw = min(window, e - s);
        int base = (bb * 3 + (cw - 1)) * SEQ;
        cS[idx] = base + s;
        cE[idx] = base + (e - cw);
        cO[idx] = m;
    } else {
        int rank = __popcll(~b & below);
        int idx = (bid * 256 - blockOff[bid]) + wI[w] + rank;
        cI[idx] = m;
    }
}

__global__ void prep_wt_old_kernel(const float* __restrict__ W, bf16* __restrict__ Wt) {
    __shared__ float tile[64][65];
    int k0 = blockIdx.x * 64;
    int n0 = blockIdx.y * 64;
    int t = threadIdx.x;
    int c = t & 63, r4 = t >> 6;
    for (int r = r4; r < 64; r += 4)
        tile[r][c] = W[(size_t)(k0 + r) * HID + n0 + c];
    __syncthreads();
    for (int r = r4; r < 64; r += 4)
        Wt[(size_t)(n0 + r) * K2 + k0 + c] = __float2bfloat16(tile[c][r]);
}

__global__ __launch_bounds__(256, 4)
void span_gemm_old_kernel(const bf16* __restrict__ M3, const bf16* __restrict__ Wt,
                          const int* __restrict__ cS, const int* __restrict__ cE,
                          const int* __restrict__ cO, const int* __restrict__ cI,
                          const int* __restrict__ cnt,
                          const float* __restrict__ bias, float* __restrict__ out) {
    __shared__ char lA[128 * 128];
    __shared__ char lB[128 * 128];
    __shared__ int rS[128], rE[128], rO[128];

    const int tid = threadIdx.x;
    const int x = blockIdx.x;
    const int g = x & 7, j = x >> 3;
    const int mt = (j / 6) * 8 + g;
    const int ns = j % 6;
    const int n0 = ns * 128;

    const int count = cnt[0];
    const int actT = (count + 127) >> 7;

    if (mt >= actT) {
        int r = (mt - actT) * 128 + (tid >> 1);
        if (r < M_TOT - count) {
            int o = cI[r];
            const float* bsrc = bias + n0 + (tid & 1) * 64;
            float* dst = out + (size_t)o * HID + n0 + (tid & 1) * 64;
#pragma unroll
            for (int c = 0; c < 16; ++c)
                *(f32x4*)(dst + c * 4) = *(const f32x4*)(bsrc + c * 4);
        }
        return;
    }

    const int m0 = mt * 128;
    if (tid < 128) {
        int m = m0 + tid;
        rS[tid] = cS[m];
        rE[tid] = cE[m];
        rO[tid] = cO[m];
    }
    __syncthreads();

    const int lane = tid & 63, w = tid >> 6;
    const int wr = w >> 1, wc = w & 1;
    const int lr = lane & 15, lg = lane >> 4;
    const int lrow8 = lane >> 3;
    const int chunkp = ((lane & 7) ^ lrow8) << 4;

    const char* aPtr[2][4];
    const char* bPtr[4];
    int ldsOff[4];
#pragma unroll
    for (int it = 0; it < 4; ++it) {
        int i = it * 4 + w;
        int r = i * 8 + lrow8;
        aPtr[0][it] = (const char*)M3 + (size_t)rS[r] * (HID * 2) + chunkp;
        aPtr[1][it] = (const char*)M3 + (size_t)rE[r] * (HID * 2) + chunkp;
        bPtr[it]    = (const char*)Wt + (size_t)(n0 + r) * (K2 * 2) + chunkp;
        ldsOff[it]  = i * 1024;
    }

    f32x4 acc[4][4];
#pragma unroll
    for (int i = 0; i < 4; i++)
#pragma unroll
        for (int j2 = 0; j2 < 4; j2++) acc[i][j2] = (f32x4){0.f, 0.f, 0.f, 0.f};

    for (int kt = 0; kt < K2; kt += 64) {
        const int half = (kt >= HID) ? 1 : 0;
        const int colB = (kt - (half ? HID : 0)) * 2;
        const int ktB  = kt * 2;
        __syncthreads();
#pragma unroll
        for (int it = 0; it < 4; ++it)
            gll16(aPtr[half][it] + colB, lA + ldsOff[it]);
#pragma unroll
        for (int it = 0; it < 4; ++it)
            gll16(bPtr[it] + ktB, lB + ldsOff[it]);
        __syncthreads();
#pragma unroll
        for (int kk = 0; kk < 2; ++kk) {
            const int cb = kk * 4 + lg;
            s16x8 af[4], bfr[4];
#pragma unroll
            for (int i = 0; i < 4; ++i) {
                int row = wr * 64 + i * 16 + lr;
                af[i] = *(const s16x8*)(lA + row * 128 + ((cb ^ (row & 7)) << 4));
            }
#pragma unroll
            for (int j2 = 0; j2 < 4; ++j2) {
                int row = wc * 64 + j2 * 16 + lr;
                bfr[j2] = *(const s16x8*)(lB + row * 128 + ((cb ^ (row & 7)) << 4));
            }
#pragma unroll
            for (int i = 0; i < 4; ++i)
#pragma unroll
                for (int j2 = 0; j2 < 4; ++j2)
                    acc[i][j2] = __builtin_amdgcn_mfma_f32_16x16x32_bf16(af[i], bfr[j2], acc[i][j2], 0, 0, 0);
        }
    }

#pragma unroll
    for (int i = 0; i < 4; i++) {
#pragma unroll
        for (int j2 = 0; j2 < 4; j2++) {
#pragma unroll
            for (int q = 0; q < 4; q++) {
                int mloc = wr * 64 + i * 16 + lg * 4 + q;
                int o = rO[mloc];
                if (o >= 0) {
                    int n = n0 + wc * 64 + j2 * 16 + lr;
                    out[(size_t)o * HID + n] = acc[i][j2][q] + bias[n];
                }
            }
        }
    }
}

// ---------------------------------------------------------------------------
extern "C" void kernel_launch(void* const* d_in, const int* in_sizes, int n_in,
                              void* d_out, int out_size, void* d_ws, size_t ws_size,
                              hipStream_t stream) {
    const float* token_reps = (const float*)d_in[0];
    const int*   span_ids   = (const int*)d_in[1];
    const int*   span_masks = (const int*)d_in[2];
    const int*   pooling    = (const int*)d_in[3];
    const float* W          = (const float*)d_in[4];
    const float* bias       = (const float*)d_in[5];
    float* out = (float*)d_out;

    char* ws = (char*)d_ws;
    int*  flag = (int*)ws;

    const size_t M3_OFF   = (size_t)2 << 20;
    const size_t M3_BYTES = (size_t)MROWS * HID * 2;          // 37,748,736
    bf16* M3 = (bf16*)(ws + M3_OFF);

    // new-path layout: M3 | Wt2 (1536x768 bf16) | P (24576x1536 bf16)
    const size_t WT2_OFF  = M3_OFF + M3_BYTES;
    const size_t WT2_BYTES = (size_t)K2 * HID * 2;            // 2,359,296
    const size_t P_OFF    = WT2_OFF + WT2_BYTES;
    const size_t P_BYTES  = (size_t)MROWS * K2 * 2;           // 75,497,472
    const size_t NEED_NEW = P_OFF + P_BYTES;                  // ~117.7 MB

    hipMemsetAsync(ws, 0, 64, stream);
    mask_detect_kernel<<<64, 256, 0, stream>>>((const unsigned*)span_masks, flag);
    prep_m3_kernel<<<dim3(SEQ / 16, NB), 256, 0, stream>>>(token_reps, M3);

    if (ws_size >= NEED_NEW) {
        bf16* Wt2 = (bf16*)(ws + WT2_OFF);
        bf16* P   = (bf16*)(ws + P_OFF);
        prep_wt2_kernel<<<dim3(HID / 64, K2 / 64), 256, 0, stream>>>(W, Wt2);
        dense_gemm_kernel<<<NWG_NEW, 256, 0, stream>>>(M3, Wt2, P);
        epilogue_kernel<<<2048, 256, 0, stream>>>(P, span_ids, span_masks, flag,
                                                  pooling, bias, out);
    } else {
        // fallback: R8's compacted gathered GEMM (fits in ~42 MB of ws)
        int* cnt      = (int*)(ws + 4);
        int* blockCnt = (int*)(ws + 1024);
        int* blockOff = (int*)(ws + 2048);
        int* cS = (int*)(ws + 4096);
        int* cE = (int*)(ws + 4096 + 4 * (size_t)CMP_CAP);
        int* cO = (int*)(ws + 4096 + 8 * (size_t)CMP_CAP);
        int* cI = (int*)(ws + 4096 + 12 * (size_t)CMP_CAP);
        bf16* WtOld = (bf16*)(ws + WT2_OFF);   // K2-stride Wt, 2.25 MB
        init_compact_kernel<<<(CMP_CAP + 255) / 256, 256, 0, stream>>>(cS, cE, cO);
        count_kernel<<<M_TOT / 256, 256, 0, stream>>>(span_masks, flag, blockCnt);
        scan_kernel<<<1, 256, 0, stream>>>(blockCnt, blockOff, cnt);
        scatter_kernel<<<M_TOT / 256, 256, 0, stream>>>(span_ids, span_masks, flag,
                                                        pooling, blockOff, cS, cE, cO, cI);
        prep_wt_old_kernel<<<dim3(K2 / 64, HID / 64), 256, 0, stream>>>(W, WtOld);
        span_gemm_old_kernel<<<NWG_OLD, 256, 0, stream>>>(
            M3, WtOld, cS, cE, cO, cI, cnt, bias, out);
    }
}